// Round 13
// baseline (102.033 us; speedup 1.0000x reference)
//
#include <hip/hip_runtime.h>
#include <hip/hip_bf16.h>

// Problem constants (fixed by setup_inputs)
#define BB   4
#define CF   256
#define CC   64
#define CP   80
#define HH   128   // hi-res
#define WW   128
#define KK   25
#define NPIX 16384 // 128*128

typedef __attribute__((ext_vector_type(8))) short short8v;
typedef __attribute__((ext_vector_type(4))) short short4v;
typedef __attribute__((ext_vector_type(4))) float f32x4;
typedef __attribute__((ext_vector_type(2))) float f32x2;

static __device__ __forceinline__ short f2bf(float f) {
  __hip_bfloat16 h = __float2bfloat16(f);
  return *reinterpret_cast<short*>(&h);
}

// ---------------- prestage: weights -> bf16 (tiny, ~2 us) ---------------
// wcb: [o][c] (64 x 256);  web: [tap][kk pad32][c] (9 x 32 x 64)
__global__ __launch_bounds__(256) void k_prestage(
    const float* __restrict__ wc, const float* __restrict__ we,
    short* __restrict__ wcb, short* __restrict__ web) {
  int idx = blockIdx.x * 256 + threadIdx.x;
  if (idx < CC * CF) wcb[idx] = f2bf(wc[idx]);
  int j = idx - CC * CF;
  if (j >= 0 && j < 9 * 32 * 64) {
    int tap = j >> 11, kk = (j >> 6) & 31, c = j & 63;
    float v = (kk < KK) ? we[(kk * 64 + c) * 9 + tap] : 0.f;
    web[j] = f2bf(v);
  }
}

// ============== MEGA: compress+conv+softmax+carafe, ONE kernel ==========
// Block = one 8x8 hi-res tile, end-to-end. Guide computed REDUNDANTLY on
// the 10x10 halo (1.56x MFMA, cheap) so guide & masks never touch global.
// grid 1024 = 4 b x 16x16 tiles. block 256 (4 waves). LDS 25.6 KB.
__global__ __launch_bounds__(256, 4) void k_mega(
    const float* __restrict__ pred, const float* __restrict__ feat,
    const short* __restrict__ wcb, const float* __restrict__ bc,
    const short* __restrict__ web, const float* __restrict__ be,
    float* __restrict__ out) {
  __shared__ char smem[18432 + 7168];
  short* Bl = (short*)smem;            // compress stage [slot128][c64 s72]
  short* Gl = (short*)smem;            // guide tile, same region/layout
  float* Pl = (float*)smem;            // carafe pred tile [cell64][50] 12.8K
  float* Ml = (float*)(smem + 18432);  // masks [px64][28] f32 7.2K
  const int tid = threadIdx.x;
  const int bx = blockIdx.x;
  const int b = bx >> 8;
  const int t = bx & 255;
  const int y0 = (t >> 4) << 3, x0 = (t & 15) << 3;
  const int wave = tid >> 6, l = tid & 63;
  const int l15 = l & 15, lh = l >> 4;

  // ---------- phase 1: compress guide for 10x10 halo (slots 0..99) ------
  // slot px_s: yp = px_s/10, xp = px_s%10 -> (y0-1+yp, x0-1+xp), clamped.
  const int px_s = tid & 127;
  const int ch0 = (tid >> 7) << 5;  // 0 or 32
  int yp = px_s / 10, xp = px_s - yp * 10;
  int gy = y0 - 1 + yp, gx = x0 - 1 + xp;
  const bool inimg = (gy >= 0) && (gy < HH) && (gx >= 0) && (gx < WW);
  int cgy = gy < 0 ? 0 : (gy > HH - 1 ? HH - 1 : gy);
  int cgx = gx < 0 ? 0 : (gx > WW - 1 ? WW - 1 : gx);
  const int goff = (cgy << 7) + cgx;
  const float* fb = feat + (size_t)b * CF * NPIX;

  f32x4 acc[4][2];
#pragma unroll
  for (int m = 0; m < 4; ++m)
#pragma unroll
    for (int n = 0; n < 2; ++n) acc[m][n] = (f32x4){0.f, 0.f, 0.f, 0.f};

  for (int c0 = 0; c0 < CF; c0 += 64) {
    if (c0) __syncthreads();
    // stage: thread covers its slot's 32 channels (2 sub-halves of 16)
#pragma unroll
    for (int h = 0; h < 2; ++h) {
      float v[16];
#pragma unroll
      for (int i = 0; i < 16; ++i)
        v[i] = fb[(size_t)(c0 + ch0 + h * 16 + i) * NPIX + goff];
      short8v h0, h1;
#pragma unroll
      for (int e = 0; e < 8; ++e) { h0[e] = f2bf(v[e]); h1[e] = f2bf(v[8 + e]); }
      *(short8v*)(Bl + px_s * 72 + ch0 + h * 16) = h0;
      *(short8v*)(Bl + px_s * 72 + ch0 + h * 16 + 8) = h1;
    }
    __syncthreads();
#pragma unroll
    for (int ks = 0; ks < 64; ks += 32) {
      short8v bfr[2];
#pragma unroll
      for (int n = 0; n < 2; ++n) {
        int slot = (wave * 2 + n) * 16 + l15;
        bfr[n] = *(const short8v*)(Bl + slot * 72 + ks + lh * 8);
      }
#pragma unroll
      for (int m = 0; m < 4; ++m) {
        short8v a =
            *(const short8v*)(wcb + (m * 16 + l15) * CF + c0 + ks + lh * 8);
#pragma unroll
        for (int n = 0; n < 2; ++n)
          acc[m][n] =
              __builtin_amdgcn_mfma_f32_16x16x32_bf16(a, bfr[n], acc[m][n], 0, 0, 0);
      }
    }
  }
  __syncthreads();  // all waves done reading Bl; overwrite with Gl

  // guide epilogue -> Gl (zero for out-of-image slots: conv zero-pad)
#pragma unroll
  for (int n = 0; n < 2; ++n) {
    int slot = (wave * 2 + n) * 16 + l15;
    if (slot < 100) {
      int syp = slot / 10, sxp = slot - syp * 10;
      int sgy = y0 - 1 + syp, sgx = x0 - 1 + sxp;
      bool vin = (sgy >= 0) && (sgy < HH) && (sgx >= 0) && (sgx < WW);
#pragma unroll
      for (int m = 0; m < 4; ++m) {
        short4v o;
#pragma unroll
        for (int r = 0; r < 4; ++r) {
          int c = m * 16 + lh * 4 + r;
          o[r] = vin ? f2bf(acc[m][n][r] + bc[c]) : (short)0;
        }
        *(short4v*)(Gl + slot * 72 + m * 16 + lh * 4) = o;
      }
    }
  }
  (void)inimg;
  __syncthreads();

  // ---------- phase 2: conv 3x3 + bias + softmax -> Ml (r4 body) --------
  {
    const int r_ = wave * 2 + (l15 >> 3);  // tile row 0..7
    const int cx = l15 & 7;                // tile col 0..7
    f32x4 acc0 = {0.f, 0.f, 0.f, 0.f}, acc1 = {0.f, 0.f, 0.f, 0.f};
#pragma unroll
    for (int tap = 0; tap < 9; ++tap) {
      const int dy = tap / 3, dx = tap - dy * 3;
#pragma unroll
      for (int ks = 0; ks < 64; ks += 32) {
        short8v a0 =
            *(const short8v*)(web + (tap * 32 + l15) * 64 + ks + lh * 8);
        short8v a1 =
            *(const short8v*)(web + (tap * 32 + 16 + l15) * 64 + ks + lh * 8);
        short8v bf = *(const short8v*)(Gl + ((r_ + dy) * 10 + cx + dx) * 72 +
                                       ks + lh * 8);
        acc0 = __builtin_amdgcn_mfma_f32_16x16x32_bf16(a0, bf, acc0, 0, 0, 0);
        acc1 = __builtin_amdgcn_mfma_f32_16x16x32_bf16(a1, bf, acc1, 0, 0, 0);
      }
    }

    float sv[8];
#pragma unroll
    for (int r = 0; r < 4; ++r) {
      int kk0 = lh * 4 + r;
      sv[r] = acc0[r] + be[kk0];
      int kk1 = 16 + lh * 4 + r;
      sv[4 + r] = (kk1 < KK) ? (acc1[r] + be[kk1]) : -1e30f;
    }
    float mx = sv[0];
#pragma unroll
    for (int i = 1; i < 8; ++i) mx = fmaxf(mx, sv[i]);
    mx = fmaxf(mx, __shfl_xor(mx, 16));
    mx = fmaxf(mx, __shfl_xor(mx, 32));
    float s = 0.f;
#pragma unroll
    for (int i = 0; i < 8; ++i) {
      sv[i] = __expf(sv[i] - mx);
      s += sv[i];
    }
    s += __shfl_xor(s, 16);
    s += __shfl_xor(s, 32);
    float inv = 1.f / s;
    int pxm = wave * 16 + l15;  // == r_*8 + cx
#pragma unroll
    for (int r = 0; r < 4; ++r) {
      Ml[pxm * 28 + lh * 4 + r] = sv[r] * inv;
      int kk1 = 16 + lh * 4 + r;
      if (kk1 < KK) Ml[pxm * 28 + kk1] = sv[4 + r] * inv;
    }
  }
  __syncthreads();  // Ml complete; Gl region free

  // ---------- phase 3: carafe, 2 ch-half passes (k_mega/r9 body) --------
  for (int rep = 0; rep < 2; ++rep) {
    if (rep) __syncthreads();  // protect Pl reuse
    const int half = rep;
    const int ylo = (y0 >> 1) - 2, xlo = (x0 >> 1) - 2;
#pragma unroll
    for (int it = 0; it < 10; ++it) {
      int idx = it * 256 + tid;          // 0..2559
      int c = idx >> 6;                  // 0..39
      int cell = idx & 63;
      int r = cell >> 3, cl = cell & 7;
      int ry = ylo + r;
      ry = ry < 0 ? -ry : (ry > 63 ? 126 - ry : ry);
      int rx = xlo + cl;
      rx = rx < 0 ? -rx : (rx > 63 ? 126 - rx : rx);
      int gg = c / 5, cc = c - gg * 5;
      Pl[cell * 50 + gg * 6 + cc] =
          pred[(((size_t)(b * CP + half * 40 + c)) << 12) + (ry << 6) + rx];
    }

    const int g = tid >> 5;              // 0..7 -> 5-ch group
    const int pr = tid & 31;             // pry(0..7) x prx(0..3)
    const int pry = pr >> 2, prx = pr & 3;
    const int lpx0 = pry * 8 + prx * 2;  // local px of pair
    float m[2][KK];
#pragma unroll
    for (int dxp = 0; dxp < 2; ++dxp) {
      const float* mb = Ml + (lpx0 + dxp) * 28;
#pragma unroll
      for (int q = 0; q < 7; ++q) {
        f32x4 mv = *(const f32x4*)(mb + q * 4);
#pragma unroll
        for (int e = 0; e < 4; ++e) {
          int kk = q * 4 + e;
          if (kk < KK) m[dxp][kk] = mv[e];
        }
      }
    }
    __syncthreads();  // Pl ready

    float acc2[5][2];
#pragma unroll
    for (int cc = 0; cc < 5; ++cc) { acc2[cc][0] = 0.f; acc2[cc][1] = 0.f; }

    const float* Pbase = Pl + ((pry >> 1) * 8 + prx) * 50 + g * 6;
#pragma unroll
    for (int i = 0; i < 5; ++i)
#pragma unroll
      for (int j = 0; j < 5; ++j) {
        const float* P = Pbase + (i * 8 + j) * 50;
        f32x2 p01 = *(const f32x2*)(P);
        f32x2 p23 = *(const f32x2*)(P + 2);
        float p4 = P[4];
        float m0 = m[0][i * 5 + j], m1 = m[1][i * 5 + j];
        acc2[0][0] += p01.x * m0; acc2[0][1] += p01.x * m1;
        acc2[1][0] += p01.y * m0; acc2[1][1] += p01.y * m1;
        acc2[2][0] += p23.x * m0; acc2[2][1] += p23.x * m1;
        acc2[3][0] += p23.y * m0; acc2[3][1] += p23.y * m1;
        acc2[4][0] += p4    * m0; acc2[4][1] += p4    * m1;
      }

    const int Y = y0 + pry, X = x0 + prx * 2;
#pragma unroll
    for (int cc = 0; cc < 5; ++cc) {
      float* ob = out + (((size_t)(b * CP + half * 40 + g * 5 + cc)) << 14) +
                  Y * WW + X;
      f32x2 v2 = {acc2[cc][0], acc2[cc][1]};
      *(f32x2*)ob = v2;
    }
  }
}

extern "C" void kernel_launch(void* const* d_in, const int* in_sizes, int n_in,
                              void* d_out, int out_size, void* d_ws,
                              size_t ws_size, hipStream_t stream) {
  (void)in_sizes; (void)n_in; (void)out_size; (void)ws_size;
  const float* pred = (const float*)d_in[0];  // (4,80,64,64)
  const float* feat = (const float*)d_in[1];  // (4,256,128,128)
  const float* wc   = (const float*)d_in[2];  // (64,256)
  const float* bc   = (const float*)d_in[3];  // (64)
  const float* we   = (const float*)d_in[4];  // (25,64,3,3)
  const float* be   = (const float*)d_in[5];  // (25)
  float* out = (float*)d_out;                 // (4,80,128,128)

  char* ws = (char*)d_ws;
  short* wcb = (short*)ws;             // 32,768 B bf16 [o][c]
  short* web = (short*)(ws + 32768);   // 36,864 B bf16 [tap][kk32][c]

  hipLaunchKernelGGL(k_prestage, dim3(136), dim3(256), 0, stream,
                     wc, we, wcb, web);
  hipLaunchKernelGGL(k_mega, dim3(1024), dim3(256), 0, stream,
                     pred, feat, wcb, bc, web, be, out);
}

// Round 14
// 59.796 us; speedup vs baseline: 1.7064x; 1.7064x over previous
//
#include <hip/hip_runtime.h>
#include <hip/hip_bf16.h>

// Problem constants (fixed by setup_inputs)
#define BB   4
#define CF   256
#define CC   64
#define CP   80
#define HH   128   // hi-res
#define WW   128
#define KK   25
#define NPIX 16384 // 128*128

typedef __attribute__((ext_vector_type(8))) short short8v;
typedef __attribute__((ext_vector_type(4))) short short4v;
typedef __attribute__((ext_vector_type(4))) float f32x4;
typedef __attribute__((ext_vector_type(2))) float f32x2;

static __device__ __forceinline__ short f2bf(float f) {
  __hip_bfloat16 h = __float2bfloat16(f);
  return *reinterpret_cast<short*>(&h);
}

// =================== K1: compress (1x1 conv) via bf16 MFMA ==============
// (byte-identical to round 9 champion — HBM-bound at ~its floor, ~13 us)
__global__ __launch_bounds__(256) void k_compress(
    const float* __restrict__ feat, const float* __restrict__ wc,
    const float* __restrict__ bc, const float* __restrict__ we,
    short* __restrict__ guide, short* __restrict__ web) {
  __shared__ short Al[32 * 520];  // [(cblk*4+lh)][o(64)*8], pad 512->520
  __shared__ short Bl[64 * 72];   // [px][c 0..63], stride 72
  const int tid = threadIdx.x;
  const int bx = blockIdx.x;
  const int b = bx >> 8;
  const int y = (bx >> 1) & 127;
  const int x0 = (bx & 1) << 6;

  // distributed web prestage: web[tap][kk pad32][c], zero for kk>=25
  {
    int j = bx * 256 + tid;
    if (j < 9 * 32 * 64) {
      int tap = j >> 11, kk = (j >> 6) & 31, c = j & 63;
      float v = (kk < KK) ? we[(kk * 64 + c) * 9 + tap] : 0.f;
      web[j] = f2bf(v);
    }
  }

  // convert wc (64x256 f32) -> Al in fragment order
#pragma unroll
  for (int t = 0; t < 8; ++t) {
    int idx = tid + t * 256;  // 0..2047
    int o = idx >> 5, c8 = idx & 31;
    const f32x4* src = (const f32x4*)(wc + o * CF + c8 * 8);
    f32x4 v0 = src[0], v1 = src[1];
    short8v h;
    h[0] = f2bf(v0.x); h[1] = f2bf(v0.y); h[2] = f2bf(v0.z); h[3] = f2bf(v0.w);
    h[4] = f2bf(v1.x); h[5] = f2bf(v1.y); h[6] = f2bf(v1.z); h[7] = f2bf(v1.w);
    int cblk = c8 >> 2, lh4 = c8 & 3;
    *(short8v*)(Al + (cblk * 4 + lh4) * 520 + o * 8) = h;
  }

  const int wave = tid >> 6, l = tid & 63;
  const int l15 = l & 15, lh = l >> 4;
  const int px_s = tid & 63;          // staging pixel
  const int c_s = (tid >> 6) << 4;    // staging channel offset (16/wave)
  const float* fb = feat + (size_t)b * CF * NPIX + y * WW + x0;

  f32x4 acc[4];
#pragma unroll
  for (int m = 0; m < 4; ++m) acc[m] = (f32x4){0.f, 0.f, 0.f, 0.f};

  for (int c0 = 0; c0 < CF; c0 += 64) {
    if (c0) __syncthreads();
    float v[16];
#pragma unroll
    for (int i = 0; i < 16; ++i)
      v[i] = fb[(size_t)(c0 + c_s + i) * NPIX + px_s];
    short8v h0, h1;
#pragma unroll
    for (int e = 0; e < 8; ++e) { h0[e] = f2bf(v[e]); h1[e] = f2bf(v[8 + e]); }
    *(short8v*)(Bl + px_s * 72 + c_s) = h0;
    *(short8v*)(Bl + px_s * 72 + c_s + 8) = h1;
    __syncthreads();  // Bl (and, first pass, Al) visible
#pragma unroll
    for (int ks = 0; ks < 64; ks += 32) {
      const int cblk = (c0 + ks) >> 5;
      short8v bfr = *(const short8v*)(Bl + (wave * 16 + l15) * 72 + ks + lh * 8);
#pragma unroll
      for (int m = 0; m < 4; ++m) {
        short8v a = *(const short8v*)(Al + (cblk * 4 + lh) * 520 +
                                      (m * 16 + l15) * 8);
        acc[m] = __builtin_amdgcn_mfma_f32_16x16x32_bf16(a, bfr, acc[m], 0, 0, 0);
      }
    }
  }

  // epilogue: +bias, cvt bf16, store [b][y][x][c]
  const int px = wave * 16 + l15;
  short* gb = guide + ((size_t)((b * HH + y) * WW + x0 + px)) * CC;
#pragma unroll
  for (int m = 0; m < 4; ++m) {
    short4v o;
#pragma unroll
    for (int r = 0; r < 4; ++r) {
      int c = m * 16 + lh * 4 + r;
      o[r] = f2bf(acc[m][r] + bc[c]);
    }
    *(short4v*)(gb + m * 16 + lh * 4) = o;
  }
}

// ====== K2: conv3x3 + softmax — WAVE-PRIVATE, ZERO barriers =============
// Each wave owns a 2x8 px strip + private LDS slice (40 px x 72 shorts).
// Same-wave ds_write -> ds_read needs only lgkmcnt (auto) — no s_barrier.
// grid 1024 x 256 (4 wave-units/block, 4096 units total). LDS 23 KB.
__global__ __launch_bounds__(256) void k_conv(
    const short* __restrict__ guide, const short* __restrict__ web,
    const float* __restrict__ be, float* __restrict__ maskq) {
  __shared__ short Gl[4 * 2880];  // per-wave [px 40][c 64 pad 72]
  const int tid = threadIdx.x;
  const int wave = tid >> 6, l = tid & 63;
  const int l15 = l & 15, lh = l >> 4;
  const int unit = blockIdx.x * 4 + wave;  // 0..4095
  const int b = unit >> 10;
  const int t = unit & 1023;
  const int y0 = (t >> 4) << 1;  // row pair 0..126
  const int x0 = (t & 15) << 3;  // col strip 0..120
  short* W = Gl + wave * 2880;

  // ---- wave-private stage: 4 rows x 10 cols halo, zero-pad ----
#pragma unroll
  for (int i = 0; i < 5; ++i) {
    int slot = i * 64 + l;           // 0..319
    int px = slot >> 3;              // 0..39
    int cq = (slot & 7) << 3;
    int hr = px / 10, hc = px - hr * 10;
    int gy = y0 - 1 + hr, gx = x0 - 1 + hc;
    short8v v = {0, 0, 0, 0, 0, 0, 0, 0};
    if (gy >= 0 && gy < HH && gx >= 0 && gx < WW)
      v = *(const short8v*)(guide + ((size_t)((b * HH + gy) * WW + gx)) * CC + cq);
    *(short8v*)(W + px * 72 + cq) = v;
  }
  // (no barrier — same-wave LDS dependency, hardware lgkmcnt orders it)

  // ---- conv MFMA: l15 -> (row l15>>3, col l15&7) in 2x8 strip ----
  const int r_ = l15 >> 3, cx = l15 & 7;
  f32x4 acc0 = {0.f, 0.f, 0.f, 0.f}, acc1 = {0.f, 0.f, 0.f, 0.f};
#pragma unroll
  for (int tap = 0; tap < 9; ++tap) {
    const int dy = tap / 3, dx = tap - dy * 3;
#pragma unroll
    for (int ks = 0; ks < 64; ks += 32) {
      short8v a0 = *(const short8v*)(web + (tap * 32 + l15) * 64 + ks + lh * 8);
      short8v a1 =
          *(const short8v*)(web + (tap * 32 + 16 + l15) * 64 + ks + lh * 8);
      short8v bf = *(const short8v*)(W + (((r_ + dy) * 10) + cx + dx) * 72 +
                                     ks + lh * 8);
      acc0 = __builtin_amdgcn_mfma_f32_16x16x32_bf16(a0, bf, acc0, 0, 0, 0);
      acc1 = __builtin_amdgcn_mfma_f32_16x16x32_bf16(a1, bf, acc1, 0, 0, 0);
    }
  }

  // ---- bias + softmax over kk (25 vals in 4 lanes: xor 16,32) ----
  float sv[8];
#pragma unroll
  for (int r = 0; r < 4; ++r) {
    int kk0 = lh * 4 + r;
    sv[r] = acc0[r] + be[kk0];
    int kk1 = 16 + lh * 4 + r;
    sv[4 + r] = (kk1 < KK) ? (acc1[r] + be[kk1]) : -1e30f;
  }
  float mx = sv[0];
#pragma unroll
  for (int i = 1; i < 8; ++i) mx = fmaxf(mx, sv[i]);
  mx = fmaxf(mx, __shfl_xor(mx, 16));
  mx = fmaxf(mx, __shfl_xor(mx, 32));
  float s = 0.f;
#pragma unroll
  for (int i = 0; i < 8; ++i) {
    sv[i] = __expf(sv[i] - mx);
    s += sv[i];
  }
  s += __shfl_xor(s, 16);
  s += __shfl_xor(s, 32);
  float inv = 1.f / s;

  // store: chunks q=lh, q=4+lh — 8 X-consecutive lanes = 128B segments
  const int Y = y0 + r_, X = x0 + cx;
  const size_t pxoff = (size_t)(Y << 7) + X;
  f32x4 o0 = {sv[0] * inv, sv[1] * inv, sv[2] * inv, sv[3] * inv};
  *(f32x4*)(maskq + ((((size_t)(b * 7 + lh)) << 14) + pxoff) * 4) = o0;
  if (lh < 3) {
    f32x4 o1 = {sv[4] * inv, sv[5] * inv, sv[6] * inv, sv[7] * inv};
    *(f32x4*)(maskq + ((((size_t)(b * 7 + 4 + lh)) << 14) + pxoff) * 4) = o1;
  }
}

// ====== K3: CARAFE — NO LDS, NO syncs, coalesced mask chunks ============
// Thread = (Y, lo-x pair xp, 5-ch group). X=2xp,2xp+1 share the 5x5 patch.
// Masks: pair chunks are 32B-contiguous; wave reads 2KB/chunk contiguous.
// pred reads lane-consecutive (coalesced), L2-resident. grid 2048 x 256.
__global__ __launch_bounds__(256) void k_carafe(
    const float* __restrict__ pred, const float* __restrict__ maskq,
    float* __restrict__ out) {
  const int tid = threadIdx.x;
  const int bx = blockIdx.x;
  const int b = bx >> 9;
  const int t = bx & 511;
  const int Y = t >> 2;
  const int g = (t & 3) * 4 + (tid >> 6);  // ch-group 0..15 (5 ch each)
  const int xp = tid & 63;                 // lo-res x == pair id
  const int X = xp << 1;

  // ---- pair masks -> registers (contiguous 32B per q per thread) ----
  float m[2][KK];
  const size_t pxoff = (size_t)(Y << 7) + X;
#pragma unroll
  for (int q = 0; q < 7; ++q) {
    const float* base = maskq + ((((size_t)(b * 7 + q)) << 14) + pxoff) * 4;
    f32x4 m0 = *(const f32x4*)(base);
    f32x4 m1 = *(const f32x4*)(base + 4);
#pragma unroll
    for (int e = 0; e < 4; ++e) {
      int kk = q * 4 + e;
      if (kk < KK) { m[0][kk] = m0[e]; m[1][kk] = m1[e]; }
    }
  }

  // ---- reflect-padded patch offsets ----
  const int iy = Y >> 1;
  int ryo[5], rxo[5];
#pragma unroll
  for (int i = 0; i < 5; ++i) {
    int ry = iy - 2 + i;
    ry = ry < 0 ? -ry : (ry > 63 ? 126 - ry : ry);
    ryo[i] = ry << 6;
    int rx = xp - 2 + i;
    rx = rx < 0 ? -rx : (rx > 63 ? 126 - rx : rx);
    rxo[i] = rx;
  }

  // ---- 5 channels x 2 px ----
  for (int cc = 0; cc < 5; ++cc) {
    const int ch = g * 5 + cc;
    const float* pb = pred + ((size_t)(b * CP + ch) << 12);
    float a0 = 0.f, a1 = 0.f;
#pragma unroll
    for (int i = 0; i < 5; ++i)
#pragma unroll
      for (int j = 0; j < 5; ++j) {
        float p = pb[ryo[i] + rxo[j]];
        a0 += p * m[0][i * 5 + j];
        a1 += p * m[1][i * 5 + j];
      }
    f32x2 v2 = {a0, a1};
    *(f32x2*)(out + ((size_t)(b * CP + ch) << 14) + (Y << 7) + X) = v2;
  }
}

extern "C" void kernel_launch(void* const* d_in, const int* in_sizes, int n_in,
                              void* d_out, int out_size, void* d_ws,
                              size_t ws_size, hipStream_t stream) {
  (void)in_sizes; (void)n_in; (void)out_size; (void)ws_size;
  const float* pred = (const float*)d_in[0];  // (4,80,64,64)
  const float* feat = (const float*)d_in[1];  // (4,256,128,128)
  const float* wc   = (const float*)d_in[2];  // (64,256)
  const float* bc   = (const float*)d_in[3];  // (64)
  const float* we   = (const float*)d_in[4];  // (25,64,3,3)
  const float* be   = (const float*)d_in[5];  // (25)
  float* out = (float*)d_out;                 // (4,80,128,128)

  char* ws = (char*)d_ws;
  short* guide = (short*)ws;                    // 8,388,608 B bf16 [b][y][x][c]
  short* web   = (short*)(ws + 8388608);        // 36,864 B bf16 [tap][kk32][c]
  float* maskq = (float*)(ws + 8388608 + 36864);// 7,340,032 B f32 [b][7][Y][X][4]

  hipLaunchKernelGGL(k_compress, dim3(1024), dim3(256), 0, stream,
                     feat, wc, bc, we, guide, web);
  hipLaunchKernelGGL(k_conv, dim3(1024), dim3(256), 0, stream,
                     guide, web, be, maskq);
  hipLaunchKernelGGL(k_carafe, dim3(2048), dim3(256), 0, stream,
                     pred, maskq, out);
}

// Round 15
// 47.620 us; speedup vs baseline: 2.1427x; 1.2557x over previous
//
#include <hip/hip_runtime.h>
#include <hip/hip_bf16.h>

// Problem constants (fixed by setup_inputs)
#define BB   4
#define CF   256
#define CC   64
#define CP   80
#define HH   128   // hi-res
#define WW   128
#define KK   25
#define NPIX 16384 // 128*128

typedef __attribute__((ext_vector_type(8))) short short8v;
typedef __attribute__((ext_vector_type(4))) short short4v;
typedef __attribute__((ext_vector_type(4))) float f32x4;
typedef __attribute__((ext_vector_type(2))) float f32x2;

static __device__ __forceinline__ short f2bf(float f) {
  __hip_bfloat16 h = __float2bfloat16(f);
  return *reinterpret_cast<short*>(&h);
}

// =================== K1: compress (1x1 conv) via bf16 MFMA ==============
// (byte-identical to round 9 champion — HBM-bound at ~its floor, ~13 us)
__global__ __launch_bounds__(256) void k_compress(
    const float* __restrict__ feat, const float* __restrict__ wc,
    const float* __restrict__ bc, const float* __restrict__ we,
    short* __restrict__ guide, short* __restrict__ web) {
  __shared__ short Al[32 * 520];  // [(cblk*4+lh)][o(64)*8], pad 512->520
  __shared__ short Bl[64 * 72];   // [px][c 0..63], stride 72
  const int tid = threadIdx.x;
  const int bx = blockIdx.x;
  const int b = bx >> 8;
  const int y = (bx >> 1) & 127;
  const int x0 = (bx & 1) << 6;

  // distributed web prestage: web[tap][kk pad32][c], zero for kk>=25
  {
    int j = bx * 256 + tid;
    if (j < 9 * 32 * 64) {
      int tap = j >> 11, kk = (j >> 6) & 31, c = j & 63;
      float v = (kk < KK) ? we[(kk * 64 + c) * 9 + tap] : 0.f;
      web[j] = f2bf(v);
    }
  }

  // convert wc (64x256 f32) -> Al in fragment order
#pragma unroll
  for (int t = 0; t < 8; ++t) {
    int idx = tid + t * 256;  // 0..2047
    int o = idx >> 5, c8 = idx & 31;
    const f32x4* src = (const f32x4*)(wc + o * CF + c8 * 8);
    f32x4 v0 = src[0], v1 = src[1];
    short8v h;
    h[0] = f2bf(v0.x); h[1] = f2bf(v0.y); h[2] = f2bf(v0.z); h[3] = f2bf(v0.w);
    h[4] = f2bf(v1.x); h[5] = f2bf(v1.y); h[6] = f2bf(v1.z); h[7] = f2bf(v1.w);
    int cblk = c8 >> 2, lh4 = c8 & 3;
    *(short8v*)(Al + (cblk * 4 + lh4) * 520 + o * 8) = h;
  }

  const int wave = tid >> 6, l = tid & 63;
  const int l15 = l & 15, lh = l >> 4;
  const int px_s = tid & 63;          // staging pixel
  const int c_s = (tid >> 6) << 4;    // staging channel offset (16/wave)
  const float* fb = feat + (size_t)b * CF * NPIX + y * WW + x0;

  f32x4 acc[4];
#pragma unroll
  for (int m = 0; m < 4; ++m) acc[m] = (f32x4){0.f, 0.f, 0.f, 0.f};

  for (int c0 = 0; c0 < CF; c0 += 64) {
    if (c0) __syncthreads();
    float v[16];
#pragma unroll
    for (int i = 0; i < 16; ++i)
      v[i] = fb[(size_t)(c0 + c_s + i) * NPIX + px_s];
    short8v h0, h1;
#pragma unroll
    for (int e = 0; e < 8; ++e) { h0[e] = f2bf(v[e]); h1[e] = f2bf(v[8 + e]); }
    *(short8v*)(Bl + px_s * 72 + c_s) = h0;
    *(short8v*)(Bl + px_s * 72 + c_s + 8) = h1;
    __syncthreads();  // Bl (and, first pass, Al) visible
#pragma unroll
    for (int ks = 0; ks < 64; ks += 32) {
      const int cblk = (c0 + ks) >> 5;
      short8v bfr = *(const short8v*)(Bl + (wave * 16 + l15) * 72 + ks + lh * 8);
#pragma unroll
      for (int m = 0; m < 4; ++m) {
        short8v a = *(const short8v*)(Al + (cblk * 4 + lh) * 520 +
                                      (m * 16 + l15) * 8);
        acc[m] = __builtin_amdgcn_mfma_f32_16x16x32_bf16(a, bfr, acc[m], 0, 0, 0);
      }
    }
  }

  // epilogue: +bias, cvt bf16, store [b][y][x][c]
  const int px = wave * 16 + l15;
  short* gb = guide + ((size_t)((b * HH + y) * WW + x0 + px)) * CC;
#pragma unroll
  for (int m = 0; m < 4; ++m) {
    short4v o;
#pragma unroll
    for (int r = 0; r < 4; ++r) {
      int c = m * 16 + lh * 4 + r;
      o[r] = f2bf(acc[m][r] + bc[c]);
    }
    *(short4v*)(gb + m * 16 + lh * 4) = o;
  }
}

// ====== K2: conv3x3 + softmax — weights in LDS in FRAGMENT ORDER ========
// The A-operand (web) was global lane-strided in every prior round
// (16-32 transactions per read, 36 reads/wave). Now: webF in LDS as 36
// frags x 1KB, lane-linear ds_read_b128 (conflict-free, 1 issue each).
// grid 1024 = 4 b x 256 tiles of 8x8 px. block 256. LDS 52.4 KB (3/CU).
__global__ __launch_bounds__(256) void k_conv(
    const short* __restrict__ guide, const short* __restrict__ web,
    const float* __restrict__ be, float* __restrict__ maskq) {
  __shared__ short Gl[10 * 10 * 72];  // guide halo [y'][x'][c], 14400 B
  __shared__ short webF[36 * 528];    // frag(tap,m,ks) x 1056B, 38016 B
  const int tid = threadIdx.x;
  const int bx = blockIdx.x;
  const int b = bx >> 8;
  const int t = bx & 255;
  const int y0 = (t >> 4) << 3, x0 = (t & 15) << 3;
  const int wave = tid >> 6, l = tid & 63;
  const int l15 = l & 15, lh = l >> 4;

  // ---- stage webF: coalesced read of web, write in fragment order ----
#pragma unroll
  for (int it = 0; it < 9; ++it) {
    int i = it * 256 + tid;  // 16B unit: i = tap*256 + kk*8 + c8
    int c8 = i & 7, kk = (i >> 3) & 31, tap = i >> 8;
    short8v v = *(const short8v*)(web + i * 8);
    int frag = tap * 4 + ((kk >> 4) << 1) + (c8 >> 2);
    int lane = (kk & 15) | ((c8 & 3) << 4);
    *(short8v*)(webF + frag * 528 + lane * 8) = v;
  }

  // ---- stage guide halo tile (zero-pad) ----
  for (int idx = tid; idx < 10 * 10 * 8; idx += 256) {
    int yp = idx / 80;
    int rem = idx - yp * 80;
    int xp = rem >> 3, cq = (rem & 7) << 3;
    int gy = y0 - 1 + yp, gx = x0 - 1 + xp;
    short8v v = {0, 0, 0, 0, 0, 0, 0, 0};
    if (gy >= 0 && gy < HH && gx >= 0 && gx < WW)
      v = *(const short8v*)(guide + ((size_t)((b * HH + gy) * WW + gx)) * CC + cq);
    *(short8v*)(Gl + (yp * 10 + xp) * 72 + cq) = v;
  }
  __syncthreads();

  // ---- conv MFMA: px = wave*16 + l15 -> (row, col) in 8x8 tile ----
  const int r_ = wave * 2 + (l15 >> 3);  // tile row 0..7
  const int cx = l15 & 7;                // tile col 0..7
  f32x4 acc0 = {0.f, 0.f, 0.f, 0.f}, acc1 = {0.f, 0.f, 0.f, 0.f};
#pragma unroll
  for (int tap = 0; tap < 9; ++tap) {
    const int dy = tap / 3, dx = tap - dy * 3;
#pragma unroll
    for (int ks32 = 0; ks32 < 2; ++ks32) {
      // lane-linear, conflict-free A reads (identical data to old path)
      short8v a0 = *(const short8v*)(webF + (tap * 4 + ks32) * 528 + l * 8);
      short8v a1 = *(const short8v*)(webF + (tap * 4 + 2 + ks32) * 528 + l * 8);
      short8v bf = *(const short8v*)(Gl + ((r_ + dy) * 10 + cx + dx) * 72 +
                                     ks32 * 32 + lh * 8);
      acc0 = __builtin_amdgcn_mfma_f32_16x16x32_bf16(a0, bf, acc0, 0, 0, 0);
      acc1 = __builtin_amdgcn_mfma_f32_16x16x32_bf16(a1, bf, acc1, 0, 0, 0);
    }
  }

  // ---- bias + softmax over kk (25 vals in 4 lanes: xor 16,32) ----
  float sv[8];
#pragma unroll
  for (int r = 0; r < 4; ++r) {
    int kk0 = lh * 4 + r;            // 0..15, always < 25
    sv[r] = acc0[r] + be[kk0];
    int kk1 = 16 + lh * 4 + r;       // 16..31
    sv[4 + r] = (kk1 < KK) ? (acc1[r] + be[kk1]) : -1e30f;
  }
  float mx = sv[0];
#pragma unroll
  for (int i = 1; i < 8; ++i) mx = fmaxf(mx, sv[i]);
  mx = fmaxf(mx, __shfl_xor(mx, 16));
  mx = fmaxf(mx, __shfl_xor(mx, 32));
  float s = 0.f;
#pragma unroll
  for (int i = 0; i < 8; ++i) {
    sv[i] = __expf(sv[i] - mx);
    s += sv[i];
  }
  s += __shfl_xor(s, 16);
  s += __shfl_xor(s, 32);
  float inv = 1.f / s;

  // store: chunk q=lh (kk 4lh..) and q=4+lh, coalesced f32x4
  const int Y = y0 + r_, X = x0 + cx;
  const size_t pxoff = (size_t)(Y << 7) + X;
  f32x4 o0 = {sv[0] * inv, sv[1] * inv, sv[2] * inv, sv[3] * inv};
  *(f32x4*)(maskq + ((((size_t)(b * 7 + lh)) << 14) + pxoff) * 4) = o0;
  if (lh < 3) {  // chunks 4,5,6 (q=6 lanes 25..27 hold zeros)
    f32x4 o1 = {sv[4] * inv, sv[5] * inv, sv[6] * inv, sv[7] * inv};
    *(f32x4*)(maskq + ((((size_t)(b * 7 + 4 + lh)) << 14) + pxoff) * 4) = o1;
  }
}

// ====== K3: CARAFE — r9 champion + masks staged to LDS coalesced ========
// The per-thread mask reads were 14 x f32x4 global gathers (32B-512B lane
// scatter). Now: one coalesced 128B-line stage into Msk[64][30] (stride 30
// -> bank-clean f32x2 reads), then LDS broadcast reads.
// grid 2048 = 4 b x 256 tiles x 2 ch-halves. block 256. LDS 20.5 KB.
__global__ __launch_bounds__(256) void k_carafe3(
    const float* __restrict__ pred, const float* __restrict__ maskq,
    float* __restrict__ out) {
  __shared__ float Pl[64 * 50];   // 12800 B
  __shared__ float Msk[64 * 30];  // 7680 B
  const int tid = threadIdx.x;
  const int bx = blockIdx.x;
  const int half = bx & 1;
  const int t = (bx >> 1) & 255;
  const int b = bx >> 9;
  const int y0 = (t >> 4) << 3, x0 = (t & 15) << 3;

  // ---- stage Pl: 40 ch x 8x8 lo cells, reflect-padded ----
  const int ylo = (y0 >> 1) - 2, xlo = (x0 >> 1) - 2;
#pragma unroll
  for (int it = 0; it < 10; ++it) {
    int idx = it * 256 + tid;          // 0..2559
    int c = idx >> 6;                  // 0..39
    int cell = idx & 63;
    int r = cell >> 3, cl = cell & 7;
    int ry = ylo + r;
    ry = ry < 0 ? -ry : (ry > 63 ? 126 - ry : ry);
    int rx = xlo + cl;
    rx = rx < 0 ? -rx : (rx > 63 ? 126 - rx : rx);
    int gg = c / 5, cc = c - gg * 5;
    Pl[cell * 50 + gg * 6 + cc] =
        pred[(((size_t)(b * CP + half * 40 + c)) << 12) + (ry << 6) + rx];
  }

  // ---- stage Msk: 7 chunks x 64 px, fully coalesced 128B lines ----
  for (int idx = tid; idx < 448; idx += 256) {
    int q = idx >> 6, pxl = idx & 63;
    int yy = pxl >> 3, xx = pxl & 7;
    f32x4 v = *(const f32x4*)(maskq + ((((size_t)(b * 7 + q)) << 14) +
                                       ((size_t)((y0 + yy) << 7)) + x0 + xx) * 4);
    float* dst = Msk + pxl * 30 + q * 4;
    *(f32x2*)dst = (f32x2){v.x, v.y};
    *(f32x2*)(dst + 2) = (f32x2){v.z, v.w};
  }
  __syncthreads();  // Pl + Msk ready

  // ---- pair masks <- LDS (bank-clean stride 30) ----
  const int g = tid >> 5;              // 0..7 -> 5-ch group
  const int pr = tid & 31;             // pry(0..7) x prx(0..3)
  const int pry = pr >> 2, prx = pr & 3;
  const int Y = y0 + pry, X = x0 + prx * 2;
  float m[2][KK];
#pragma unroll
  for (int dxp = 0; dxp < 2; ++dxp) {
    const float* mb = Msk + (pry * 8 + prx * 2 + dxp) * 30;
#pragma unroll
    for (int q = 0; q < 7; ++q) {
      f32x2 lo = *(const f32x2*)(mb + q * 4);
      f32x2 hi = *(const f32x2*)(mb + q * 4 + 2);
      int kk = q * 4;
      m[dxp][kk] = lo.x;
      if (kk + 1 < KK) m[dxp][kk + 1] = lo.y;
      if (kk + 2 < KK) m[dxp][kk + 2] = hi.x;
      if (kk + 3 < KK) m[dxp][kk + 3] = hi.y;
    }
  }

  // ---- carafe: 5 ch x 2 px per thread ----
  float acc[5][2];
#pragma unroll
  for (int cc = 0; cc < 5; ++cc) { acc[cc][0] = 0.f; acc[cc][1] = 0.f; }

  const float* Pbase = Pl + ((pry >> 1) * 8 + prx) * 50 + g * 6;
#pragma unroll
  for (int i = 0; i < 5; ++i)
#pragma unroll
    for (int j = 0; j < 5; ++j) {
      const float* P = Pbase + (i * 8 + j) * 50;
      f32x2 p01 = *(const f32x2*)(P);
      f32x2 p23 = *(const f32x2*)(P + 2);
      float p4 = P[4];
      float m0 = m[0][i * 5 + j], m1 = m[1][i * 5 + j];
      acc[0][0] += p01.x * m0; acc[0][1] += p01.x * m1;
      acc[1][0] += p01.y * m0; acc[1][1] += p01.y * m1;
      acc[2][0] += p23.x * m0; acc[2][1] += p23.x * m1;
      acc[3][0] += p23.y * m0; acc[3][1] += p23.y * m1;
      acc[4][0] += p4    * m0; acc[4][1] += p4    * m1;
    }

#pragma unroll
  for (int cc = 0; cc < 5; ++cc) {
    float* ob = out + (((size_t)(b * CP + half * 40 + g * 5 + cc)) << 14) +
                Y * WW + X;
    f32x2 v2 = {acc[cc][0], acc[cc][1]};
    *(f32x2*)ob = v2;
  }
}

extern "C" void kernel_launch(void* const* d_in, const int* in_sizes, int n_in,
                              void* d_out, int out_size, void* d_ws,
                              size_t ws_size, hipStream_t stream) {
  (void)in_sizes; (void)n_in; (void)out_size; (void)ws_size;
  const float* pred = (const float*)d_in[0];  // (4,80,64,64)
  const float* feat = (const float*)d_in[1];  // (4,256,128,128)
  const float* wc   = (const float*)d_in[2];  // (64,256)
  const float* bc   = (const float*)d_in[3];  // (64)
  const float* we   = (const float*)d_in[4];  // (25,64,3,3)
  const float* be   = (const float*)d_in[5];  // (25)
  float* out = (float*)d_out;                 // (4,80,128,128)

  char* ws = (char*)d_ws;
  short* guide = (short*)ws;                    // 8,388,608 B bf16 [b][y][x][c]
  short* web   = (short*)(ws + 8388608);        // 36,864 B bf16 [tap][kk32][c]
  float* maskq = (float*)(ws + 8388608 + 36864);// 7,340,032 B f32 [b][7][Y][X][4]

  hipLaunchKernelGGL(k_compress, dim3(1024), dim3(256), 0, stream,
                     feat, wc, bc, we, guide, web);
  hipLaunchKernelGGL(k_conv, dim3(1024), dim3(256), 0, stream,
                     guide, web, be, maskq);
  hipLaunchKernelGGL(k_carafe3, dim3(2048), dim3(256), 0, stream,
                     pred, maskq, out);
}

// Round 16
// 45.473 us; speedup vs baseline: 2.2438x; 1.0472x over previous
//
#include <hip/hip_runtime.h>
#include <hip/hip_bf16.h>

// Problem constants (fixed by setup_inputs)
#define BB   4
#define CF   256
#define CC   64
#define CP   80
#define HH   128   // hi-res
#define WW   128
#define KK   25
#define NPIX 16384 // 128*128

typedef __attribute__((ext_vector_type(8))) short short8v;
typedef __attribute__((ext_vector_type(4))) short short4v;
typedef __attribute__((ext_vector_type(4))) float f32x4;
typedef __attribute__((ext_vector_type(2))) float f32x2;

static __device__ __forceinline__ short f2bf(float f) {
  __hip_bfloat16 h = __float2bfloat16(f);
  return *reinterpret_cast<short*>(&h);
}

// =================== K1: compress (1x1 conv) via bf16 MFMA ==============
// (byte-identical to round 9/15 champion — HBM-bound at ~its floor)
__global__ __launch_bounds__(256) void k_compress(
    const float* __restrict__ feat, const float* __restrict__ wc,
    const float* __restrict__ bc, const float* __restrict__ we,
    short* __restrict__ guide, short* __restrict__ web) {
  __shared__ short Al[32 * 520];  // [(cblk*4+lh)][o(64)*8], pad 512->520
  __shared__ short Bl[64 * 72];   // [px][c 0..63], stride 72
  const int tid = threadIdx.x;
  const int bx = blockIdx.x;
  const int b = bx >> 8;
  const int y = (bx >> 1) & 127;
  const int x0 = (bx & 1) << 6;

  // distributed web prestage: web[tap][kk pad32][c], zero for kk>=25
  {
    int j = bx * 256 + tid;
    if (j < 9 * 32 * 64) {
      int tap = j >> 11, kk = (j >> 6) & 31, c = j & 63;
      float v = (kk < KK) ? we[(kk * 64 + c) * 9 + tap] : 0.f;
      web[j] = f2bf(v);
    }
  }

  // convert wc (64x256 f32) -> Al in fragment order
#pragma unroll
  for (int t = 0; t < 8; ++t) {
    int idx = tid + t * 256;  // 0..2047
    int o = idx >> 5, c8 = idx & 31;
    const f32x4* src = (const f32x4*)(wc + o * CF + c8 * 8);
    f32x4 v0 = src[0], v1 = src[1];
    short8v h;
    h[0] = f2bf(v0.x); h[1] = f2bf(v0.y); h[2] = f2bf(v0.z); h[3] = f2bf(v0.w);
    h[4] = f2bf(v1.x); h[5] = f2bf(v1.y); h[6] = f2bf(v1.z); h[7] = f2bf(v1.w);
    int cblk = c8 >> 2, lh4 = c8 & 3;
    *(short8v*)(Al + (cblk * 4 + lh4) * 520 + o * 8) = h;
  }

  const int wave = tid >> 6, l = tid & 63;
  const int l15 = l & 15, lh = l >> 4;
  const int px_s = tid & 63;          // staging pixel
  const int c_s = (tid >> 6) << 4;    // staging channel offset (16/wave)
  const float* fb = feat + (size_t)b * CF * NPIX + y * WW + x0;

  f32x4 acc[4];
#pragma unroll
  for (int m = 0; m < 4; ++m) acc[m] = (f32x4){0.f, 0.f, 0.f, 0.f};

  for (int c0 = 0; c0 < CF; c0 += 64) {
    if (c0) __syncthreads();
    float v[16];
#pragma unroll
    for (int i = 0; i < 16; ++i)
      v[i] = fb[(size_t)(c0 + c_s + i) * NPIX + px_s];
    short8v h0, h1;
#pragma unroll
    for (int e = 0; e < 8; ++e) { h0[e] = f2bf(v[e]); h1[e] = f2bf(v[8 + e]); }
    *(short8v*)(Bl + px_s * 72 + c_s) = h0;
    *(short8v*)(Bl + px_s * 72 + c_s + 8) = h1;
    __syncthreads();  // Bl (and, first pass, Al) visible
#pragma unroll
    for (int ks = 0; ks < 64; ks += 32) {
      const int cblk = (c0 + ks) >> 5;
      short8v bfr = *(const short8v*)(Bl + (wave * 16 + l15) * 72 + ks + lh * 8);
#pragma unroll
      for (int m = 0; m < 4; ++m) {
        short8v a = *(const short8v*)(Al + (cblk * 4 + lh) * 520 +
                                      (m * 16 + l15) * 8);
        acc[m] = __builtin_amdgcn_mfma_f32_16x16x32_bf16(a, bfr, acc[m], 0, 0, 0);
      }
    }
  }

  // epilogue: +bias, cvt bf16, store [b][y][x][c]
  const int px = wave * 16 + l15;
  short* gb = guide + ((size_t)((b * HH + y) * WW + x0 + px)) * CC;
#pragma unroll
  for (int m = 0; m < 4; ++m) {
    short4v o;
#pragma unroll
    for (int r = 0; r < 4; ++r) {
      int c = m * 16 + lh * 4 + r;
      o[r] = f2bf(acc[m][r] + bc[c]);
    }
    *(short4v*)(gb + m * 16 + lh * 4) = o;
  }
}

// ====== K2: conv+softmax+CARAFE fused — masks never leave LDS ===========
// Phase A = r15 k_conv body (webF fragment-order LDS weights);
// softmax -> Ml (LDS, r15 Msk layout) instead of global maskq.
// Phase B = r15 k_carafe3 body x 2 ch-halves; m[2][25] hoisted across both.
// grid 1024 = 4 b x 256 tiles of 8x8 px. block 256. LDS 51.3 KB (3/CU).
__global__ __launch_bounds__(256) void k_fused(
    const short* __restrict__ guide, const short* __restrict__ web,
    const float* __restrict__ be, const float* __restrict__ pred,
    float* __restrict__ out) {
  __shared__ char smem[36864 + 14400];
  short* webF = (short*)smem;             // 36 frags x 512 shorts = 36864 B
  short* Gl = (short*)(smem + 36864);     // [y'10][x'10][c72] = 14400 B
  float* Ml = (float*)smem;               // [px64][30] = 7680 B (post-conv)
  float* Pl = (float*)(smem + 36864);     // [cell64][50] = 12800 B (post-conv)
  const int tid = threadIdx.x;
  const int bx = blockIdx.x;
  const int b = bx >> 8;
  const int t = bx & 255;
  const int y0 = (t >> 4) << 3, x0 = (t & 15) << 3;
  const int wave = tid >> 6, l = tid & 63;
  const int l15 = l & 15, lh = l >> 4;

  // ---- stage webF: coalesced read of web, write in fragment order ----
#pragma unroll
  for (int it = 0; it < 9; ++it) {
    int i = it * 256 + tid;  // 16B unit: i = tap*256 + kk*8 + c8
    int c8 = i & 7, kk = (i >> 3) & 31, tap = i >> 8;
    short8v v = *(const short8v*)(web + i * 8);
    int frag = tap * 4 + ((kk >> 4) << 1) + (c8 >> 2);
    int lane = (kk & 15) | ((c8 & 3) << 4);
    *(short8v*)(webF + frag * 512 + lane * 8) = v;
  }

  // ---- stage guide halo tile (zero-pad) ----
  for (int idx = tid; idx < 10 * 10 * 8; idx += 256) {
    int yp = idx / 80;
    int rem = idx - yp * 80;
    int xp = rem >> 3, cq = (rem & 7) << 3;
    int gy = y0 - 1 + yp, gx = x0 - 1 + xp;
    short8v v = {0, 0, 0, 0, 0, 0, 0, 0};
    if (gy >= 0 && gy < HH && gx >= 0 && gx < WW)
      v = *(const short8v*)(guide + ((size_t)((b * HH + gy) * WW + gx)) * CC + cq);
    *(short8v*)(Gl + (yp * 10 + xp) * 72 + cq) = v;
  }
  __syncthreads();

  // ---- conv MFMA: px = wave*16 + l15 -> (row, col) in 8x8 tile ----
  const int r_ = wave * 2 + (l15 >> 3);  // tile row 0..7
  const int cx = l15 & 7;                // tile col 0..7
  f32x4 acc0 = {0.f, 0.f, 0.f, 0.f}, acc1 = {0.f, 0.f, 0.f, 0.f};
#pragma unroll
  for (int tap = 0; tap < 9; ++tap) {
    const int dy = tap / 3, dx = tap - dy * 3;
#pragma unroll
    for (int ks32 = 0; ks32 < 2; ++ks32) {
      short8v a0 = *(const short8v*)(webF + (tap * 4 + ks32) * 512 + l * 8);
      short8v a1 = *(const short8v*)(webF + (tap * 4 + 2 + ks32) * 512 + l * 8);
      short8v bf = *(const short8v*)(Gl + ((r_ + dy) * 10 + cx + dx) * 72 +
                                     ks32 * 32 + lh * 8);
      acc0 = __builtin_amdgcn_mfma_f32_16x16x32_bf16(a0, bf, acc0, 0, 0, 0);
      acc1 = __builtin_amdgcn_mfma_f32_16x16x32_bf16(a1, bf, acc1, 0, 0, 0);
    }
  }

  // ---- bias + softmax over kk (25 vals in 4 lanes: xor 16,32) ----
  float sv[8];
#pragma unroll
  for (int r = 0; r < 4; ++r) {
    int kk0 = lh * 4 + r;            // 0..15, always < 25
    sv[r] = acc0[r] + be[kk0];
    int kk1 = 16 + lh * 4 + r;       // 16..31
    sv[4 + r] = (kk1 < KK) ? (acc1[r] + be[kk1]) : -1e30f;
  }
  float mx = sv[0];
#pragma unroll
  for (int i = 1; i < 8; ++i) mx = fmaxf(mx, sv[i]);
  mx = fmaxf(mx, __shfl_xor(mx, 16));
  mx = fmaxf(mx, __shfl_xor(mx, 32));
  float s = 0.f;
#pragma unroll
  for (int i = 0; i < 8; ++i) {
    sv[i] = __expf(sv[i] - mx);
    s += sv[i];
  }
  s += __shfl_xor(s, 16);
  s += __shfl_xor(s, 32);
  float inv = 1.f / s;

  __syncthreads();  // ALL waves done reading webF/Gl; regions become Ml/Pl

  // ---- write Ml[px][30] (stride 30 -> conflict-clean scalar stores) ----
  {
    int pxm = wave * 16 + l15;  // == r_*8 + cx
#pragma unroll
    for (int r = 0; r < 4; ++r) {
      Ml[pxm * 30 + lh * 4 + r] = sv[r] * inv;
      if (lh < 3) Ml[pxm * 30 + 16 + lh * 4 + r] = sv[4 + r] * inv;
    }
  }

  // ---- carafe thread roles (r15) ----
  const int g = tid >> 5;              // 0..7 -> 5-ch group
  const int pr = tid & 31;             // pry(0..7) x prx(0..3)
  const int pry = pr >> 2, prx = pr & 3;
  const int Y = y0 + pry, X = x0 + prx * 2;
  const int ylo = (y0 >> 1) - 2, xlo = (x0 >> 1) - 2;

  float m[2][KK];
  const float* Pbase = Pl + ((pry >> 1) * 8 + prx) * 50 + g * 6;

  for (int half = 0; half < 2; ++half) {
    // stage Pl for this half (first pass overlaps Ml writes; disjoint region)
#pragma unroll
    for (int it = 0; it < 10; ++it) {
      int idx = it * 256 + tid;          // 0..2559
      int c = idx >> 6;                  // 0..39
      int cell = idx & 63;
      int r = cell >> 3, cl = cell & 7;
      int ry = ylo + r;
      ry = ry < 0 ? -ry : (ry > 63 ? 126 - ry : ry);
      int rx = xlo + cl;
      rx = rx < 0 ? -rx : (rx > 63 ? 126 - rx : rx);
      int gg = c / 5, cc = c - gg * 5;
      Pl[cell * 50 + gg * 6 + cc] =
          pred[(((size_t)(b * CP + half * 40 + c)) << 12) + (ry << 6) + rx];
    }
    __syncthreads();  // Pl (and, half 0, Ml) ready

    if (half == 0) {
      // hoist pair masks once — same for both halves
#pragma unroll
      for (int dxp = 0; dxp < 2; ++dxp) {
        const float* mb = Ml + (pry * 8 + prx * 2 + dxp) * 30;
#pragma unroll
        for (int q = 0; q < 7; ++q) {
          f32x2 lo = *(const f32x2*)(mb + q * 4);
          f32x2 hi = *(const f32x2*)(mb + q * 4 + 2);
          int kk = q * 4;
          m[dxp][kk] = lo.x;
          if (kk + 1 < KK) m[dxp][kk + 1] = lo.y;
          if (kk + 2 < KK) m[dxp][kk + 2] = hi.x;
          if (kk + 3 < KK) m[dxp][kk + 3] = hi.y;
        }
      }
    }

    float acc[5][2];
#pragma unroll
    for (int cc = 0; cc < 5; ++cc) { acc[cc][0] = 0.f; acc[cc][1] = 0.f; }

#pragma unroll
    for (int i = 0; i < 5; ++i)
#pragma unroll
      for (int j = 0; j < 5; ++j) {
        const float* P = Pbase + (i * 8 + j) * 50;
        f32x2 p01 = *(const f32x2*)(P);
        f32x2 p23 = *(const f32x2*)(P + 2);
        float p4 = P[4];
        float m0 = m[0][i * 5 + j], m1 = m[1][i * 5 + j];
        acc[0][0] += p01.x * m0; acc[0][1] += p01.x * m1;
        acc[1][0] += p01.y * m0; acc[1][1] += p01.y * m1;
        acc[2][0] += p23.x * m0; acc[2][1] += p23.x * m1;
        acc[3][0] += p23.y * m0; acc[3][1] += p23.y * m1;
        acc[4][0] += p4    * m0; acc[4][1] += p4    * m1;
      }

#pragma unroll
    for (int cc = 0; cc < 5; ++cc) {
      float* ob = out + (((size_t)(b * CP + half * 40 + g * 5 + cc)) << 14) +
                  Y * WW + X;
      f32x2 v2 = {acc[cc][0], acc[cc][1]};
      *(f32x2*)ob = v2;
    }
    if (half == 0) __syncthreads();  // protect Pl before restaging
  }
}

extern "C" void kernel_launch(void* const* d_in, const int* in_sizes, int n_in,
                              void* d_out, int out_size, void* d_ws,
                              size_t ws_size, hipStream_t stream) {
  (void)in_sizes; (void)n_in; (void)out_size; (void)ws_size;
  const float* pred = (const float*)d_in[0];  // (4,80,64,64)
  const float* feat = (const float*)d_in[1];  // (4,256,128,128)
  const float* wc   = (const float*)d_in[2];  // (64,256)
  const float* bc   = (const float*)d_in[3];  // (64)
  const float* we   = (const float*)d_in[4];  // (25,64,3,3)
  const float* be   = (const float*)d_in[5];  // (25)
  float* out = (float*)d_out;                 // (4,80,128,128)

  char* ws = (char*)d_ws;
  short* guide = (short*)ws;             // 8,388,608 B bf16 [b][y][x][c]
  short* web   = (short*)(ws + 8388608); // 36,864 B bf16 [tap][kk32][c]

  hipLaunchKernelGGL(k_compress, dim3(1024), dim3(256), 0, stream,
                     feat, wc, bc, we, guide, web);
  hipLaunchKernelGGL(k_fused, dim3(1024), dim3(256), 0, stream,
                     guide, web, be, pred, out);
}

// Round 17
// 42.940 us; speedup vs baseline: 2.3762x; 1.0590x over previous
//
#include <hip/hip_runtime.h>
#include <hip/hip_bf16.h>

// Problem constants (fixed by setup_inputs)
#define BB   4
#define CF   256
#define CC   64
#define CP   80
#define HH   128   // hi-res
#define WW   128
#define KK   25
#define NPIX 16384 // 128*128

typedef __attribute__((ext_vector_type(8))) short short8v;
typedef __attribute__((ext_vector_type(4))) short short4v;
typedef __attribute__((ext_vector_type(4))) float f32x4;
typedef __attribute__((ext_vector_type(2))) float f32x2;

static __device__ __forceinline__ short f2bf(float f) {
  __hip_bfloat16 h = __float2bfloat16(f);
  return *reinterpret_cast<short*>(&h);
}

// =================== K1: compress (1x1 conv) via bf16 MFMA ==============
// Body byte-identical to round 9/15 champion (HBM-bound at ~its floor).
// Change: distributed weight prestage now writes webF in MFMA FRAGMENT
// ORDER directly (frag*512 + lane*8 + e), so the consumer reads it from
// global with lane-linear 1KB-contiguous loads (no LDS staging needed).
__global__ __launch_bounds__(256) void k_compress(
    const float* __restrict__ feat, const float* __restrict__ wc,
    const float* __restrict__ bc, const float* __restrict__ we,
    short* __restrict__ guide, short* __restrict__ webF) {
  __shared__ short Al[32 * 520];  // [(cblk*4+lh)][o(64)*8], pad 512->520
  __shared__ short Bl[64 * 72];   // [px][c 0..63], stride 72
  const int tid = threadIdx.x;
  const int bx = blockIdx.x;
  const int b = bx >> 8;
  const int y = (bx >> 1) & 127;
  const int x0 = (bx & 1) << 6;

  // distributed webF prestage in fragment order (mapping HW-verified r15)
  {
    int j = bx * 256 + tid;
    if (j < 9 * 32 * 64) {
      int tap = j >> 11, kk = (j >> 6) & 31, c = j & 63;
      float v = (kk < KK) ? we[(kk * 64 + c) * 9 + tap] : 0.f;
      int c8 = c >> 3, e = c & 7;
      int frag = tap * 4 + ((kk >> 4) << 1) + (c8 >> 2);
      int lane = (kk & 15) | ((c8 & 3) << 4);
      webF[frag * 512 + lane * 8 + e] = f2bf(v);
    }
  }

  // convert wc (64x256 f32) -> Al in fragment order
#pragma unroll
  for (int t = 0; t < 8; ++t) {
    int idx = tid + t * 256;  // 0..2047
    int o = idx >> 5, c8 = idx & 31;
    const f32x4* src = (const f32x4*)(wc + o * CF + c8 * 8);
    f32x4 v0 = src[0], v1 = src[1];
    short8v h;
    h[0] = f2bf(v0.x); h[1] = f2bf(v0.y); h[2] = f2bf(v0.z); h[3] = f2bf(v0.w);
    h[4] = f2bf(v1.x); h[5] = f2bf(v1.y); h[6] = f2bf(v1.z); h[7] = f2bf(v1.w);
    int cblk = c8 >> 2, lh4 = c8 & 3;
    *(short8v*)(Al + (cblk * 4 + lh4) * 520 + o * 8) = h;
  }

  const int wave = tid >> 6, l = tid & 63;
  const int l15 = l & 15, lh = l >> 4;
  const int px_s = tid & 63;          // staging pixel
  const int c_s = (tid >> 6) << 4;    // staging channel offset (16/wave)
  const float* fb = feat + (size_t)b * CF * NPIX + y * WW + x0;

  f32x4 acc[4];
#pragma unroll
  for (int m = 0; m < 4; ++m) acc[m] = (f32x4){0.f, 0.f, 0.f, 0.f};

  for (int c0 = 0; c0 < CF; c0 += 64) {
    if (c0) __syncthreads();
    float v[16];
#pragma unroll
    for (int i = 0; i < 16; ++i)
      v[i] = fb[(size_t)(c0 + c_s + i) * NPIX + px_s];
    short8v h0, h1;
#pragma unroll
    for (int e = 0; e < 8; ++e) { h0[e] = f2bf(v[e]); h1[e] = f2bf(v[8 + e]); }
    *(short8v*)(Bl + px_s * 72 + c_s) = h0;
    *(short8v*)(Bl + px_s * 72 + c_s + 8) = h1;
    __syncthreads();  // Bl (and, first pass, Al) visible
#pragma unroll
    for (int ks = 0; ks < 64; ks += 32) {
      const int cblk = (c0 + ks) >> 5;
      short8v bfr = *(const short8v*)(Bl + (wave * 16 + l15) * 72 + ks + lh * 8);
#pragma unroll
      for (int m = 0; m < 4; ++m) {
        short8v a = *(const short8v*)(Al + (cblk * 4 + lh) * 520 +
                                      (m * 16 + l15) * 8);
        acc[m] = __builtin_amdgcn_mfma_f32_16x16x32_bf16(a, bfr, acc[m], 0, 0, 0);
      }
    }
  }

  // epilogue: +bias, cvt bf16, store [b][y][x][c]
  const int px = wave * 16 + l15;
  short* gb = guide + ((size_t)((b * HH + y) * WW + x0 + px)) * CC;
#pragma unroll
  for (int m = 0; m < 4; ++m) {
    short4v o;
#pragma unroll
    for (int r = 0; r < 4; ++r) {
      int c = m * 16 + lh * 4 + r;
      o[r] = f2bf(acc[m][r] + bc[c]);
    }
    *(short4v*)(gb + m * 16 + lh * 4) = o;
  }
}

// ====== K2: conv+softmax+CARAFE fused — webF from GLOBAL, lean LDS ======
// A-fragments: lane-linear 1KB-contiguous global reads (L1-resident).
// LDS only Gl (14.4K) overlaid by Ml(7.7K)+Pl(12.8K) = 20.5 KB total.
// grid 1024 = 4 b x 256 tiles of 8x8 px. block 256, 4+ blocks/CU.
__global__ __launch_bounds__(256, 4) void k_fused(
    const short* __restrict__ guide, const short* __restrict__ webF,
    const float* __restrict__ be, const float* __restrict__ pred,
    float* __restrict__ out) {
  __shared__ char smem[20480];
  short* Gl = (short*)smem;               // [y'10][x'10][c72] = 14400 B
  float* Ml = (float*)smem;               // [px64][30] = 7680 B (post-conv)
  float* Pl = (float*)(smem + 7680);      // [cell64][50] = 12800 B (post-conv)
  const int tid = threadIdx.x;
  const int bx = blockIdx.x;
  const int b = bx >> 8;
  const int t = bx & 255;
  const int y0 = (t >> 4) << 3, x0 = (t & 15) << 3;
  const int wave = tid >> 6, l = tid & 63;
  const int l15 = l & 15, lh = l >> 4;

  // ---- stage guide halo tile (zero-pad) ----
  for (int idx = tid; idx < 10 * 10 * 8; idx += 256) {
    int yp = idx / 80;
    int rem = idx - yp * 80;
    int xp = rem >> 3, cq = (rem & 7) << 3;
    int gy = y0 - 1 + yp, gx = x0 - 1 + xp;
    short8v v = {0, 0, 0, 0, 0, 0, 0, 0};
    if (gy >= 0 && gy < HH && gx >= 0 && gx < WW)
      v = *(const short8v*)(guide + ((size_t)((b * HH + gy) * WW + gx)) * CC + cq);
    *(short8v*)(Gl + (yp * 10 + xp) * 72 + cq) = v;
  }
  __syncthreads();

  // ---- conv MFMA: px = wave*16 + l15 -> (row, col) in 8x8 tile ----
  const int r_ = wave * 2 + (l15 >> 3);  // tile row 0..7
  const int cx = l15 & 7;                // tile col 0..7
  f32x4 acc0 = {0.f, 0.f, 0.f, 0.f}, acc1 = {0.f, 0.f, 0.f, 0.f};
#pragma unroll
  for (int tap = 0; tap < 9; ++tap) {
    const int dy = tap / 3, dx = tap - dy * 3;
#pragma unroll
    for (int ks32 = 0; ks32 < 2; ++ks32) {
      // lane-linear global reads: 64 lanes x 16B = 1KB contiguous, L1-hot
      short8v a0 = *(const short8v*)(webF + (tap * 4 + ks32) * 512 + l * 8);
      short8v a1 = *(const short8v*)(webF + (tap * 4 + 2 + ks32) * 512 + l * 8);
      short8v bf = *(const short8v*)(Gl + ((r_ + dy) * 10 + cx + dx) * 72 +
                                     ks32 * 32 + lh * 8);
      acc0 = __builtin_amdgcn_mfma_f32_16x16x32_bf16(a0, bf, acc0, 0, 0, 0);
      acc1 = __builtin_amdgcn_mfma_f32_16x16x32_bf16(a1, bf, acc1, 0, 0, 0);
    }
  }

  // ---- bias + softmax over kk (25 vals in 4 lanes: xor 16,32) ----
  float sv[8];
#pragma unroll
  for (int r = 0; r < 4; ++r) {
    int kk0 = lh * 4 + r;            // 0..15, always < 25
    sv[r] = acc0[r] + be[kk0];
    int kk1 = 16 + lh * 4 + r;       // 16..31
    sv[4 + r] = (kk1 < KK) ? (acc1[r] + be[kk1]) : -1e30f;
  }
  float mx = sv[0];
#pragma unroll
  for (int i = 1; i < 8; ++i) mx = fmaxf(mx, sv[i]);
  mx = fmaxf(mx, __shfl_xor(mx, 16));
  mx = fmaxf(mx, __shfl_xor(mx, 32));
  float s = 0.f;
#pragma unroll
  for (int i = 0; i < 8; ++i) {
    sv[i] = __expf(sv[i] - mx);
    s += sv[i];
  }
  s += __shfl_xor(s, 16);
  s += __shfl_xor(s, 32);
  float inv = 1.f / s;

  __syncthreads();  // ALL waves done reading Gl; region becomes Ml/Pl

  // ---- write Ml[px][30] (stride 30 -> conflict-clean scalar stores) ----
  {
    int pxm = wave * 16 + l15;  // == r_*8 + cx
#pragma unroll
    for (int r = 0; r < 4; ++r) {
      Ml[pxm * 30 + lh * 4 + r] = sv[r] * inv;
      if (lh < 3) Ml[pxm * 30 + 16 + lh * 4 + r] = sv[4 + r] * inv;
    }
  }

  // ---- carafe thread roles (r15) ----
  const int g = tid >> 5;              // 0..7 -> 5-ch group
  const int pr = tid & 31;             // pry(0..7) x prx(0..3)
  const int pry = pr >> 2, prx = pr & 3;
  const int Y = y0 + pry, X = x0 + prx * 2;
  const int ylo = (y0 >> 1) - 2, xlo = (x0 >> 1) - 2;

  float m[2][KK];
  const float* Pbase = Pl + ((pry >> 1) * 8 + prx) * 50 + g * 6;

  for (int half = 0; half < 2; ++half) {
    // stage Pl for this half (disjoint from Ml region)
#pragma unroll
    for (int it = 0; it < 10; ++it) {
      int idx = it * 256 + tid;          // 0..2559
      int c = idx >> 6;                  // 0..39
      int cell = idx & 63;
      int r = cell >> 3, cl = cell & 7;
      int ry = ylo + r;
      ry = ry < 0 ? -ry : (ry > 63 ? 126 - ry : ry);
      int rx = xlo + cl;
      rx = rx < 0 ? -rx : (rx > 63 ? 126 - rx : rx);
      int gg = c / 5, cc = c - gg * 5;
      Pl[cell * 50 + gg * 6 + cc] =
          pred[(((size_t)(b * CP + half * 40 + c)) << 12) + (ry << 6) + rx];
    }
    __syncthreads();  // Pl (and, half 0, Ml) ready

    if (half == 0) {
      // hoist pair masks once — same for both halves
#pragma unroll
      for (int dxp = 0; dxp < 2; ++dxp) {
        const float* mb = Ml + (pry * 8 + prx * 2 + dxp) * 30;
#pragma unroll
        for (int q = 0; q < 7; ++q) {
          f32x2 lo = *(const f32x2*)(mb + q * 4);
          f32x2 hi = *(const f32x2*)(mb + q * 4 + 2);
          int kk = q * 4;
          m[dxp][kk] = lo.x;
          if (kk + 1 < KK) m[dxp][kk + 1] = lo.y;
          if (kk + 2 < KK) m[dxp][kk + 2] = hi.x;
          if (kk + 3 < KK) m[dxp][kk + 3] = hi.y;
        }
      }
    }

    float acc[5][2];
#pragma unroll
    for (int cc = 0; cc < 5; ++cc) { acc[cc][0] = 0.f; acc[cc][1] = 0.f; }

#pragma unroll
    for (int i = 0; i < 5; ++i)
#pragma unroll
      for (int j = 0; j < 5; ++j) {
        const float* P = Pbase + (i * 8 + j) * 50;
        f32x2 p01 = *(const f32x2*)(P);
        f32x2 p23 = *(const f32x2*)(P + 2);
        float p4 = P[4];
        float m0 = m[0][i * 5 + j], m1 = m[1][i * 5 + j];
        acc[0][0] += p01.x * m0; acc[0][1] += p01.x * m1;
        acc[1][0] += p01.y * m0; acc[1][1] += p01.y * m1;
        acc[2][0] += p23.x * m0; acc[2][1] += p23.x * m1;
        acc[3][0] += p23.y * m0; acc[3][1] += p23.y * m1;
        acc[4][0] += p4    * m0; acc[4][1] += p4    * m1;
      }

#pragma unroll
    for (int cc = 0; cc < 5; ++cc) {
      float* ob = out + (((size_t)(b * CP + half * 40 + g * 5 + cc)) << 14) +
                  Y * WW + X;
      f32x2 v2 = {acc[cc][0], acc[cc][1]};
      *(f32x2*)ob = v2;
    }
    if (half == 0) __syncthreads();  // protect Pl before restaging
  }
}

extern "C" void kernel_launch(void* const* d_in, const int* in_sizes, int n_in,
                              void* d_out, int out_size, void* d_ws,
                              size_t ws_size, hipStream_t stream) {
  (void)in_sizes; (void)n_in; (void)out_size; (void)ws_size;
  const float* pred = (const float*)d_in[0];  // (4,80,64,64)
  const float* feat = (const float*)d_in[1];  // (4,256,128,128)
  const float* wc   = (const float*)d_in[2];  // (64,256)
  const float* bc   = (const float*)d_in[3];  // (64)
  const float* we   = (const float*)d_in[4];  // (25,64,3,3)
  const float* be   = (const float*)d_in[5];  // (25)
  float* out = (float*)d_out;                 // (4,80,128,128)

  char* ws = (char*)d_ws;
  short* guide = (short*)ws;             // 8,388,608 B bf16 [b][y][x][c]
  short* webF  = (short*)(ws + 8388608); // 36,864 B bf16 fragment-order

  hipLaunchKernelGGL(k_compress, dim3(1024), dim3(256), 0, stream,
                     feat, wc, bc, we, guide, webF);
  hipLaunchKernelGGL(k_fused, dim3(1024), dim3(256), 0, stream,
                     guide, webF, be, pred, out);
}

// Round 18
// 41.731 us; speedup vs baseline: 2.4450x; 1.0290x over previous
//
#include <hip/hip_runtime.h>
#include <hip/hip_bf16.h>

// Problem constants (fixed by setup_inputs)
#define BB   4
#define CF   256
#define CC   64
#define CP   80
#define HH   128   // hi-res
#define WW   128
#define KK   25
#define NPIX 16384 // 128*128

typedef __attribute__((ext_vector_type(8))) short short8v;
typedef __attribute__((ext_vector_type(4))) short short4v;
typedef __attribute__((ext_vector_type(4))) float f32x4;
typedef __attribute__((ext_vector_type(2))) float f32x2;

static __device__ __forceinline__ short f2bf(float f) {
  __hip_bfloat16 h = __float2bfloat16(f);
  return *reinterpret_cast<short*>(&h);
}

// =================== K1: compress (1x1 conv) via bf16 MFMA ==============
// (byte-identical to round 17 — HBM-bound at ~81% of achievable BW)
__global__ __launch_bounds__(256) void k_compress(
    const float* __restrict__ feat, const float* __restrict__ wc,
    const float* __restrict__ bc, const float* __restrict__ we,
    short* __restrict__ guide, short* __restrict__ webF) {
  __shared__ short Al[32 * 520];  // [(cblk*4+lh)][o(64)*8], pad 512->520
  __shared__ short Bl[64 * 72];   // [px][c 0..63], stride 72
  const int tid = threadIdx.x;
  const int bx = blockIdx.x;
  const int b = bx >> 8;
  const int y = (bx >> 1) & 127;
  const int x0 = (bx & 1) << 6;

  // distributed webF prestage in fragment order (mapping HW-verified r15)
  {
    int j = bx * 256 + tid;
    if (j < 9 * 32 * 64) {
      int tap = j >> 11, kk = (j >> 6) & 31, c = j & 63;
      float v = (kk < KK) ? we[(kk * 64 + c) * 9 + tap] : 0.f;
      int c8 = c >> 3, e = c & 7;
      int frag = tap * 4 + ((kk >> 4) << 1) + (c8 >> 2);
      int lane = (kk & 15) | ((c8 & 3) << 4);
      webF[frag * 512 + lane * 8 + e] = f2bf(v);
    }
  }

  // convert wc (64x256 f32) -> Al in fragment order
#pragma unroll
  for (int t = 0; t < 8; ++t) {
    int idx = tid + t * 256;  // 0..2047
    int o = idx >> 5, c8 = idx & 31;
    const f32x4* src = (const f32x4*)(wc + o * CF + c8 * 8);
    f32x4 v0 = src[0], v1 = src[1];
    short8v h;
    h[0] = f2bf(v0.x); h[1] = f2bf(v0.y); h[2] = f2bf(v0.z); h[3] = f2bf(v0.w);
    h[4] = f2bf(v1.x); h[5] = f2bf(v1.y); h[6] = f2bf(v1.z); h[7] = f2bf(v1.w);
    int cblk = c8 >> 2, lh4 = c8 & 3;
    *(short8v*)(Al + (cblk * 4 + lh4) * 520 + o * 8) = h;
  }

  const int wave = tid >> 6, l = tid & 63;
  const int l15 = l & 15, lh = l >> 4;
  const int px_s = tid & 63;          // staging pixel
  const int c_s = (tid >> 6) << 4;    // staging channel offset (16/wave)
  const float* fb = feat + (size_t)b * CF * NPIX + y * WW + x0;

  f32x4 acc[4];
#pragma unroll
  for (int m = 0; m < 4; ++m) acc[m] = (f32x4){0.f, 0.f, 0.f, 0.f};

  for (int c0 = 0; c0 < CF; c0 += 64) {
    if (c0) __syncthreads();
    float v[16];
#pragma unroll
    for (int i = 0; i < 16; ++i)
      v[i] = fb[(size_t)(c0 + c_s + i) * NPIX + px_s];
    short8v h0, h1;
#pragma unroll
    for (int e = 0; e < 8; ++e) { h0[e] = f2bf(v[e]); h1[e] = f2bf(v[8 + e]); }
    *(short8v*)(Bl + px_s * 72 + c_s) = h0;
    *(short8v*)(Bl + px_s * 72 + c_s + 8) = h1;
    __syncthreads();  // Bl (and, first pass, Al) visible
#pragma unroll
    for (int ks = 0; ks < 64; ks += 32) {
      const int cblk = (c0 + ks) >> 5;
      short8v bfr = *(const short8v*)(Bl + (wave * 16 + l15) * 72 + ks + lh * 8);
#pragma unroll
      for (int m = 0; m < 4; ++m) {
        short8v a = *(const short8v*)(Al + (cblk * 4 + lh) * 520 +
                                      (m * 16 + l15) * 8);
        acc[m] = __builtin_amdgcn_mfma_f32_16x16x32_bf16(a, bfr, acc[m], 0, 0, 0);
      }
    }
  }

  // epilogue: +bias, cvt bf16, store [b][y][x][c]
  const int px = wave * 16 + l15;
  short* gb = guide + ((size_t)((b * HH + y) * WW + x0 + px)) * CC;
#pragma unroll
  for (int m = 0; m < 4; ++m) {
    short4v o;
#pragma unroll
    for (int r = 0; r < 4; ++r) {
      int c = m * 16 + lh * 4 + r;
      o[r] = f2bf(acc[m][r] + bc[c]);
    }
    *(short4v*)(gb + m * 16 + lh * 4) = o;
  }
}

// ====== K2: fused conv+softmax+carafe — T14 async-STAGE pred loads ======
// r17 body with ONE change: pred loads issued into registers EARLY
// (pv0 before conv MFMA, pv1 before carafe half0) and written to LDS
// LATE (after the barrier that frees the region) — HBM/L2 latency hides
// under the intervening compute phase. Same barrier count.
__global__ __launch_bounds__(256, 4) void k_fused(
    const short* __restrict__ guide, const short* __restrict__ webF,
    const float* __restrict__ be, const float* __restrict__ pred,
    float* __restrict__ out) {
  __shared__ char smem[20480];
  short* Gl = (short*)smem;               // [y'10][x'10][c72] = 14400 B
  float* Ml = (float*)smem;               // [px64][30] = 7680 B (post-conv)
  float* Pl = (float*)(smem + 7680);      // [cell64][50] = 12800 B (post-conv)
  const int tid = threadIdx.x;
  const int bx = blockIdx.x;
  const int b = bx >> 8;
  const int t = bx & 255;
  const int y0 = (t >> 4) << 3, x0 = (t & 15) << 3;
  const int wave = tid >> 6, l = tid & 63;
  const int l15 = l & 15, lh = l >> 4;

  // ---- stage guide halo tile (zero-pad) ----
  for (int idx = tid; idx < 10 * 10 * 8; idx += 256) {
    int yp = idx / 80;
    int rem = idx - yp * 80;
    int xp = rem >> 3, cq = (rem & 7) << 3;
    int gy = y0 - 1 + yp, gx = x0 - 1 + xp;
    short8v v = {0, 0, 0, 0, 0, 0, 0, 0};
    if (gy >= 0 && gy < HH && gx >= 0 && gx < WW)
      v = *(const short8v*)(guide + ((size_t)((b * HH + gy) * WW + gx)) * CC + cq);
    *(short8v*)(Gl + (yp * 10 + xp) * 72 + cq) = v;
  }

  // ---- T14 issue: half-0 pred loads -> registers (hide under conv) ----
  const int ylo = (y0 >> 1) - 2, xlo = (x0 >> 1) - 2;
  int pcell[10], pslot[10];  // cached addressing for the write-back
#pragma unroll
  for (int it = 0; it < 10; ++it) {
    int idx = it * 256 + tid;
    int c = idx >> 6;
    int cell = idx & 63;
    int r = cell >> 3, cl = cell & 7;
    int ry = ylo + r;
    ry = ry < 0 ? -ry : (ry > 63 ? 126 - ry : ry);
    int rx = xlo + cl;
    rx = rx < 0 ? -rx : (rx > 63 ? 126 - rx : rx);
    int gg = c / 5, cc = c - gg * 5;
    pcell[it] = cell;
    pslot[it] = gg * 6 + cc;
    // stash global offset pieces in registers via immediate use below
  }
  float pv0[10];
#pragma unroll
  for (int it = 0; it < 10; ++it) {
    int idx = it * 256 + tid;
    int c = idx >> 6;
    int cell = idx & 63;
    int r = cell >> 3, cl = cell & 7;
    int ry = ylo + r;
    ry = ry < 0 ? -ry : (ry > 63 ? 126 - ry : ry);
    int rx = xlo + cl;
    rx = rx < 0 ? -rx : (rx > 63 ? 126 - rx : rx);
    pv0[it] = pred[(((size_t)(b * CP + c)) << 12) + (ry << 6) + rx];
  }
  __syncthreads();  // Gl ready

  // ---- conv MFMA (pv0 loads in flight underneath) ----
  const int r_ = wave * 2 + (l15 >> 3);  // tile row 0..7
  const int cx = l15 & 7;                // tile col 0..7
  f32x4 acc0 = {0.f, 0.f, 0.f, 0.f}, acc1 = {0.f, 0.f, 0.f, 0.f};
#pragma unroll
  for (int tap = 0; tap < 9; ++tap) {
    const int dy = tap / 3, dx = tap - dy * 3;
#pragma unroll
    for (int ks32 = 0; ks32 < 2; ++ks32) {
      short8v a0 = *(const short8v*)(webF + (tap * 4 + ks32) * 512 + l * 8);
      short8v a1 = *(const short8v*)(webF + (tap * 4 + 2 + ks32) * 512 + l * 8);
      short8v bf = *(const short8v*)(Gl + ((r_ + dy) * 10 + cx + dx) * 72 +
                                     ks32 * 32 + lh * 8);
      acc0 = __builtin_amdgcn_mfma_f32_16x16x32_bf16(a0, bf, acc0, 0, 0, 0);
      acc1 = __builtin_amdgcn_mfma_f32_16x16x32_bf16(a1, bf, acc1, 0, 0, 0);
    }
  }

  // ---- bias + softmax over kk (25 vals in 4 lanes: xor 16,32) ----
  float sv[8];
#pragma unroll
  for (int r = 0; r < 4; ++r) {
    int kk0 = lh * 4 + r;            // 0..15, always < 25
    sv[r] = acc0[r] + be[kk0];
    int kk1 = 16 + lh * 4 + r;       // 16..31
    sv[4 + r] = (kk1 < KK) ? (acc1[r] + be[kk1]) : -1e30f;
  }
  float mx = sv[0];
#pragma unroll
  for (int i = 1; i < 8; ++i) mx = fmaxf(mx, sv[i]);
  mx = fmaxf(mx, __shfl_xor(mx, 16));
  mx = fmaxf(mx, __shfl_xor(mx, 32));
  float s = 0.f;
#pragma unroll
  for (int i = 0; i < 8; ++i) {
    sv[i] = __expf(sv[i] - mx);
    s += sv[i];
  }
  s += __shfl_xor(s, 16);
  s += __shfl_xor(s, 32);
  float inv = 1.f / s;

  __syncthreads();  // ALL waves done reading Gl; region becomes Ml/Pl

  // ---- write Ml[px][30] + write-back pv0 -> Pl ----
  {
    int pxm = wave * 16 + l15;  // == r_*8 + cx
#pragma unroll
    for (int r = 0; r < 4; ++r) {
      Ml[pxm * 30 + lh * 4 + r] = sv[r] * inv;
      if (lh < 3) Ml[pxm * 30 + 16 + lh * 4 + r] = sv[4 + r] * inv;
    }
  }
#pragma unroll
  for (int it = 0; it < 10; ++it)
    Pl[pcell[it] * 50 + pslot[it]] = pv0[it];

  // ---- T14 issue: half-1 pred loads (hide under carafe half-0) ----
  float pv1[10];
#pragma unroll
  for (int it = 0; it < 10; ++it) {
    int idx = it * 256 + tid;
    int c = idx >> 6;
    int cell = idx & 63;
    int r = cell >> 3, cl = cell & 7;
    int ry = ylo + r;
    ry = ry < 0 ? -ry : (ry > 63 ? 126 - ry : ry);
    int rx = xlo + cl;
    rx = rx < 0 ? -rx : (rx > 63 ? 126 - rx : rx);
    pv1[it] = pred[(((size_t)(b * CP + 40 + c)) << 12) + (ry << 6) + rx];
  }
  __syncthreads();  // Ml + Pl(half0) ready

  // ---- carafe thread roles (r15) ----
  const int g = tid >> 5;              // 0..7 -> 5-ch group
  const int pr = tid & 31;             // pry(0..7) x prx(0..3)
  const int pry = pr >> 2, prx = pr & 3;
  const int Y = y0 + pry, X = x0 + prx * 2;
  const float* Pbase = Pl + ((pry >> 1) * 8 + prx) * 50 + g * 6;

  // hoist pair masks once — same for both halves
  float m[2][KK];
#pragma unroll
  for (int dxp = 0; dxp < 2; ++dxp) {
    const float* mb = Ml + (pry * 8 + prx * 2 + dxp) * 30;
#pragma unroll
    for (int q = 0; q < 7; ++q) {
      f32x2 lo = *(const f32x2*)(mb + q * 4);
      f32x2 hi = *(const f32x2*)(mb + q * 4 + 2);
      int kk = q * 4;
      m[dxp][kk] = lo.x;
      if (kk + 1 < KK) m[dxp][kk + 1] = lo.y;
      if (kk + 2 < KK) m[dxp][kk + 2] = hi.x;
      if (kk + 3 < KK) m[dxp][kk + 3] = hi.y;
    }
  }

  for (int half = 0; half < 2; ++half) {
    if (half == 1) {
      __syncthreads();  // Pl(half0) dead
#pragma unroll
      for (int it = 0; it < 10; ++it)
        Pl[pcell[it] * 50 + pslot[it]] = pv1[it];
      __syncthreads();  // Pl(half1) ready
    }

    float acc[5][2];
#pragma unroll
    for (int cc = 0; cc < 5; ++cc) { acc[cc][0] = 0.f; acc[cc][1] = 0.f; }

#pragma unroll
    for (int i = 0; i < 5; ++i)
#pragma unroll
      for (int j = 0; j < 5; ++j) {
        const float* P = Pbase + (i * 8 + j) * 50;
        f32x2 p01 = *(const f32x2*)(P);
        f32x2 p23 = *(const f32x2*)(P + 2);
        float p4 = P[4];
        float m0 = m[0][i * 5 + j], m1 = m[1][i * 5 + j];
        acc[0][0] += p01.x * m0; acc[0][1] += p01.x * m1;
        acc[1][0] += p01.y * m0; acc[1][1] += p01.y * m1;
        acc[2][0] += p23.x * m0; acc[2][1] += p23.x * m1;
        acc[3][0] += p23.y * m0; acc[3][1] += p23.y * m1;
        acc[4][0] += p4    * m0; acc[4][1] += p4    * m1;
      }

#pragma unroll
    for (int cc = 0; cc < 5; ++cc) {
      float* ob = out + (((size_t)(b * CP + half * 40 + g * 5 + cc)) << 14) +
                  Y * WW + X;
      f32x2 v2 = {acc[cc][0], acc[cc][1]};
      *(f32x2*)ob = v2;
    }
  }
}

extern "C" void kernel_launch(void* const* d_in, const int* in_sizes, int n_in,
                              void* d_out, int out_size, void* d_ws,
                              size_t ws_size, hipStream_t stream) {
  (void)in_sizes; (void)n_in; (void)out_size; (void)ws_size;
  const float* pred = (const float*)d_in[0];  // (4,80,64,64)
  const float* feat = (const float*)d_in[1];  // (4,256,128,128)
  const float* wc   = (const float*)d_in[2];  // (64,256)
  const float* bc   = (const float*)d_in[3];  // (64)
  const float* we   = (const float*)d_in[4];  // (25,64,3,3)
  const float* be   = (const float*)d_in[5];  // (25)
  float* out = (float*)d_out;                 // (4,80,128,128)

  char* ws = (char*)d_ws;
  short* guide = (short*)ws;             // 8,388,608 B bf16 [b][y][x][c]
  short* webF  = (short*)(ws + 8388608); // 36,864 B bf16 fragment-order

  hipLaunchKernelGGL(k_compress, dim3(1024), dim3(256), 0, stream,
                     feat, wc, bc, we, guide, webF);
  hipLaunchKernelGGL(k_fused, dim3(1024), dim3(256), 0, stream,
                     guide, webF, be, pred, out);
}